// Round 1
// baseline (424.192 us; speedup 1.0000x reference)
//
#include <hip/hip_runtime.h>
#include <math.h>

// Problem constants (fixed by setup_inputs)
#define B  4
#define N  512
#define BN (B * N)
#define H  64
#define I  128

#define PI_F   3.14159265358979323846f
#define Y0_F   160.0f
#define Y1_F   155.4930028f   // 160 - 320*(1-1e-5)/71
#define INV_W  (1.0f / 800.0f)

__device__ __forceinline__ float gelu_exact(float x) {
    return 0.5f * x * (1.0f + erff(x * 0.70710678118654752f));
}

// ---------------------------------------------------------------------------
// Kernel A: per-node precompute.
//  feats = relu(bf @ W_cls + b_cls)                       [BN,64]
//  u = feats@W_in  + b_in  + p@W_pos + b_pos              [BN,128]
//  v = feats@W_out + b_out + p@W_pos                      [BN,128]
//  U = u @ W_e1 + b_e1 ;  V = v @ W_e1                    [BN,128]
// Then edge1[b,i,j,:] = U[b,i] - V[b,j]  exactly.
// ---------------------------------------------------------------------------
#define NPB 8   // nodes per block

__global__ __launch_bounds__(256) void prep_kernel(
    const float* __restrict__ bf, const float* __restrict__ emb,
    const float* __restrict__ W_cls, const float* __restrict__ b_cls,
    const float* __restrict__ W_pos, const float* __restrict__ b_pos,
    const float* __restrict__ W_in,  const float* __restrict__ b_in,
    const float* __restrict__ W_out, const float* __restrict__ b_out,
    const float* __restrict__ W_e1,  const float* __restrict__ b_e1,
    float* __restrict__ Uo, float* __restrict__ Vo)
{
    __shared__ float sbf[NPB][64];
    __shared__ float sft[NPB][64];
    __shared__ float su[NPB][128];
    __shared__ float sv[NPB][128];

    const int tid = threadIdx.x;
    const int node0 = blockIdx.x * NPB;

    // stage input rows
    for (int idx = tid; idx < NPB * 64; idx += 256) {
        int nd = idx >> 6, d = idx & 63;
        sbf[nd][d] = bf[(node0 + nd) * 64 + d];
    }
    __syncthreads();

    // feats = relu(bf @ W_cls + b_cls)
    {
        int nd = tid >> 6, h = tid & 63;
        for (int rep = 0; rep < NPB / 4; ++rep) {
            int n2 = nd + rep * 4;
            float acc = b_cls[h];
            #pragma unroll 8
            for (int d = 0; d < 64; ++d) acc += sbf[n2][d] * W_cls[d * 64 + h];
            sft[n2][h] = fmaxf(acc, 0.0f);
        }
    }
    __syncthreads();

    // u, v
    {
        int k = tid & 127, half = tid >> 7;
        for (int rep = 0; rep < NPB / 2; ++rep) {
            int nd = half + rep * 2;
            int g = node0 + nd;
            float e0 = emb[g * 2], e1 = emb[g * 2 + 1];
            float ang = e0 * PI_F;
            float t = tanf(ang);
            float rc = (e1 * 800.0f) / cosf(ang);
            float p0 = (-t * Y0_F + rc) * INV_W;
            float p1 = (-t * Y1_F + rc) * INV_W;
            float pe = p0 * W_pos[k] + p1 * W_pos[128 + k];
            float au = b_in[k] + b_pos[k] + pe;
            float av = b_out[k] + pe;
            #pragma unroll 8
            for (int h = 0; h < 64; ++h) {
                float f = sft[nd][h];
                au += f * W_in[h * 128 + k];
                av += f * W_out[h * 128 + k];
            }
            su[nd][k] = au;
            sv[nd][k] = av;
        }
    }
    __syncthreads();

    // U = u@W_e1 + b_e1 ; V = v@W_e1
    {
        int k = tid & 127, half = tid >> 7;
        for (int rep = 0; rep < NPB / 2; ++rep) {
            int nd = half + rep * 2;
            float aU = b_e1[k];
            float aV = 0.0f;
            #pragma unroll 8
            for (int m = 0; m < 128; ++m) {
                float w = W_e1[m * 128 + k];
                aU += su[nd][m] * w;
                aV += sv[nd][m] * w;
            }
            int g = (node0 + nd) * 128 + k;
            Uo[g] = aU;
            Vo[g] = aV;
        }
    }
}

// ---------------------------------------------------------------------------
// Kernel B: one block per output column (b,j).
//  edge2[i] = sum_k gelu(U[b,i,k]-V[b,j,k]) * W_e2[k] + b_e2
//  nm = max_i ( supress(i,j) ? edge2[i] : 0 )   (diagonal always 0 -> init 0)
//  head: relu(nm*W_n1+b_n1) -> relu(@W_n2+b_n2) -> @W_head+b_head -> sigmoid
//  cls_pred[col] < 0.4  -> output exactly 0 (skip everything)
// ---------------------------------------------------------------------------
__global__ __launch_bounds__(256) void edge_kernel(
    const float* __restrict__ U, const float* __restrict__ V,
    const float* __restrict__ cls, const int* __restrict__ aid,
    const float* __restrict__ emb,
    const float* __restrict__ W_e2, const float* __restrict__ b_e2,
    const float* __restrict__ W_n1, const float* __restrict__ b_n1,
    const float* __restrict__ W_n2, const float* __restrict__ b_n2,
    const float* __restrict__ W_hd, const float* __restrict__ b_hd,
    float* __restrict__ out)
{
    const int col = blockIdx.x;           // b*N + j
    const int tid = threadIdx.x;
    const float cls_j = cls[col];
    if (cls_j < 0.4f) {                   // masked column: sigmoid(-1e6) == 0
        if (tid == 0) out[col] = 0.0f;
        return;
    }

    __shared__ float Vs[128];
    __shared__ float w2s[128];
    __shared__ float red[256];
    __shared__ float n1s[64];

    if (tid < 128) {
        Vs[tid]  = V[col * 128 + tid];
        w2s[tid] = W_e2[tid];
    }
    const float ang_j = emb[col * 2] * PI_F;
    const int   id_j  = aid[col];
    const float be2   = b_e2[0];
    const int rowbase = (col >> 9) << 9;  // b*N
    __syncthreads();

    float runmax = 0.0f;
    for (int i = tid; i < N; i += 256) {
        int gi = rowbase + i;
        float cls_i = cls[gi];
        bool m = (cls_i > cls_j) || (cls_i == cls_j && aid[gi] > id_j);
        if (m) {
            float ang_i = emb[gi * 2] * PI_F;
            m = fabsf(ang_i - ang_j) < 0.5f;
        }
        if (m) {
            const float4* Up = (const float4*)(U + gi * 128);
            float s = be2;
            #pragma unroll
            for (int k4 = 0; k4 < 32; ++k4) {
                float4 u4 = Up[k4];
                int k = k4 * 4;
                s += gelu_exact(u4.x - Vs[k + 0]) * w2s[k + 0];
                s += gelu_exact(u4.y - Vs[k + 1]) * w2s[k + 1];
                s += gelu_exact(u4.z - Vs[k + 2]) * w2s[k + 2];
                s += gelu_exact(u4.w - Vs[k + 3]) * w2s[k + 3];
            }
            runmax = fmaxf(runmax, s);
        }
    }

    red[tid] = runmax;
    __syncthreads();
    for (int sft = 128; sft > 0; sft >>= 1) {
        if (tid < sft) red[tid] = fmaxf(red[tid], red[tid + sft]);
        __syncthreads();
    }
    const float nm = red[0];

    // head MLP (single wave)
    if (tid < 64) {
        n1s[tid] = fmaxf(nm * W_n1[tid] + b_n1[tid], 0.0f);
    }
    __syncthreads();
    if (tid < 64) {
        float a = b_n2[tid];
        #pragma unroll 8
        for (int m2 = 0; m2 < 64; ++m2) a += n1s[m2] * W_n2[m2 * 64 + tid];
        a = fmaxf(a, 0.0f);
        float p = a * W_hd[tid];
        for (int off = 32; off > 0; off >>= 1) p += __shfl_down(p, off);
        if (tid == 0) {
            float logit = p + b_hd[0];
            out[col] = 1.0f / (1.0f + expf(-logit));
        }
    }
}

extern "C" void kernel_launch(void* const* d_in, const int* in_sizes, int n_in,
                              void* d_out, int out_size, void* d_ws, size_t ws_size,
                              hipStream_t stream) {
    const float* bf    = (const float*)d_in[0];
    const float* cls   = (const float*)d_in[1];
    const int*   aid   = (const int*)  d_in[2];
    const float* emb   = (const float*)d_in[3];
    const float* W_cls = (const float*)d_in[4];
    const float* b_cls = (const float*)d_in[5];
    const float* W_pos = (const float*)d_in[6];
    const float* b_pos = (const float*)d_in[7];
    const float* W_in  = (const float*)d_in[8];
    const float* b_in  = (const float*)d_in[9];
    const float* W_out = (const float*)d_in[10];
    const float* b_out = (const float*)d_in[11];
    const float* W_e1  = (const float*)d_in[12];
    const float* b_e1  = (const float*)d_in[13];
    const float* W_e2  = (const float*)d_in[14];
    const float* b_e2  = (const float*)d_in[15];
    const float* W_n1  = (const float*)d_in[16];
    const float* b_n1  = (const float*)d_in[17];
    const float* W_n2  = (const float*)d_in[18];
    const float* b_n2  = (const float*)d_in[19];
    const float* W_hd  = (const float*)d_in[20];
    const float* b_hd  = (const float*)d_in[21];

    float* Uw = (float*)d_ws;            // [BN,128]
    float* Vw = Uw + BN * I;             // [BN,128]
    float* out = (float*)d_out;

    prep_kernel<<<BN / NPB, 256, 0, stream>>>(
        bf, emb, W_cls, b_cls, W_pos, b_pos, W_in, b_in, W_out, b_out,
        W_e1, b_e1, Uw, Vw);
    edge_kernel<<<BN, 256, 0, stream>>>(
        Uw, Vw, cls, aid, emb, W_e2, b_e2, W_n1, b_n1, W_n2, b_n2,
        W_hd, b_hd, out);
}

// Round 2
// 182.913 us; speedup vs baseline: 2.3191x; 2.3191x over previous
//
#include <hip/hip_runtime.h>
#include <math.h>

// Problem constants (fixed by setup_inputs)
#define B  4
#define N  512
#define BN (B * N)
#define H  64
#define I  128

#define PI_F   3.14159265358979323846f
#define Y0_F   160.0f
#define Y1_F   155.4930028f   // 160 - 320*(1-1e-5)/71
#define INV_W  (1.0f / 800.0f)

__device__ __forceinline__ float gelu_exact(float x) {
    return 0.5f * x * (1.0f + erff(x * 0.70710678118654752f));
}

// ---------------------------------------------------------------------------
// Kernel A: per-node precompute (algebraic collapse of all per-edge matmuls).
//  feats = relu(bf @ W_cls + b_cls)                       [BN,64]
//  u = feats@W_in  + b_in  + p@W_pos + b_pos              [BN,128]
//  v = feats@W_out + b_out + p@W_pos                      [BN,128]
//  U = u @ W_e1 + b_e1 ;  V = v @ W_e1                    [BN,128]
// Then edge1[b,i,j,:] = U[b,i] - V[b,j]  exactly.
// ---------------------------------------------------------------------------
#define NPB 4   // nodes per block -> 512 blocks (2/CU)

__global__ __launch_bounds__(256) void prep_kernel(
    const float* __restrict__ bf, const float* __restrict__ emb,
    const float* __restrict__ W_cls, const float* __restrict__ b_cls,
    const float* __restrict__ W_pos, const float* __restrict__ b_pos,
    const float* __restrict__ W_in,  const float* __restrict__ b_in,
    const float* __restrict__ W_out, const float* __restrict__ b_out,
    const float* __restrict__ W_e1,  const float* __restrict__ b_e1,
    float* __restrict__ Uo, float* __restrict__ Vo)
{
    __shared__ float sbf[NPB][64];
    __shared__ float sft[NPB][64];
    __shared__ float su[NPB][128];
    __shared__ float sv[NPB][128];

    const int tid = threadIdx.x;
    const int node0 = blockIdx.x * NPB;

    // stage input rows (one value per thread)
    {
        int nd = tid >> 6, d = tid & 63;
        sbf[nd][d] = bf[(node0 + nd) * 64 + d];
    }
    __syncthreads();

    // feats = relu(bf @ W_cls + b_cls)
    {
        int nd = tid >> 6, h = tid & 63;
        float acc = b_cls[h];
        #pragma unroll 8
        for (int d = 0; d < 64; ++d) acc += sbf[nd][d] * W_cls[d * 64 + h];
        sft[nd][h] = fmaxf(acc, 0.0f);
    }
    __syncthreads();

    // u, v
    {
        int k = tid & 127, half = tid >> 7;
        for (int rep = 0; rep < NPB / 2; ++rep) {
            int nd = half + rep * 2;
            int g = node0 + nd;
            float e0 = emb[g * 2], e1 = emb[g * 2 + 1];
            float ang = e0 * PI_F;
            float t = tanf(ang);
            float rc = (e1 * 800.0f) / cosf(ang);
            float p0 = (-t * Y0_F + rc) * INV_W;
            float p1 = (-t * Y1_F + rc) * INV_W;
            float pe = p0 * W_pos[k] + p1 * W_pos[128 + k];
            float au = b_in[k] + b_pos[k] + pe;
            float av = b_out[k] + pe;
            #pragma unroll 8
            for (int h = 0; h < 64; ++h) {
                float f = sft[nd][h];
                au += f * W_in[h * 128 + k];
                av += f * W_out[h * 128 + k];
            }
            su[nd][k] = au;
            sv[nd][k] = av;
        }
    }
    __syncthreads();

    // U = u@W_e1 + b_e1 ; V = v@W_e1
    {
        int k = tid & 127, half = tid >> 7;
        for (int rep = 0; rep < NPB / 2; ++rep) {
            int nd = half + rep * 2;
            float aU = b_e1[k];
            float aV = 0.0f;
            #pragma unroll 8
            for (int m = 0; m < 128; ++m) {
                float w = W_e1[m * 128 + k];
                aU += su[nd][m] * w;
                aV += sv[nd][m] * w;
            }
            int g = (node0 + nd) * 128 + k;
            Uo[g] = aU;
            Vo[g] = aV;
        }
    }
}

// ---------------------------------------------------------------------------
// Kernel B: ONE WAVE PER COLUMN (4 columns/block).
// Phase 1: wave compacts active rows (mask) into an LDS list via ballot.
// Phase 2: each lane processes whole compacted rows densely (128 gelu each).
// Phase 3: wave max-reduce -> tiny head MLP -> sigmoid.
// ---------------------------------------------------------------------------
__global__ __launch_bounds__(256) void edge_kernel(
    const float* __restrict__ U, const float* __restrict__ V,
    const float* __restrict__ cls, const int* __restrict__ aid,
    const float* __restrict__ emb,
    const float* __restrict__ W_e2, const float* __restrict__ b_e2,
    const float* __restrict__ W_n1, const float* __restrict__ b_n1,
    const float* __restrict__ W_n2, const float* __restrict__ b_n2,
    const float* __restrict__ W_hd, const float* __restrict__ b_hd,
    float* __restrict__ out)
{
    const int tid  = threadIdx.x;
    const int wave = tid >> 6;
    const int lane = tid & 63;
    const int col  = blockIdx.x * 4 + wave;   // b*N + j

    __shared__ float w2s[128];
    __shared__ float Vsh[4][128];
    __shared__ unsigned short lists[4][512];
    __shared__ float n1sh[4][64];

    if (tid < 128) w2s[tid] = W_e2[tid];
    __syncthreads();   // all threads reach this (no divergence yet)

    const float cls_j = cls[col];
    if (cls_j < 0.4f) {                 // masked column: sigmoid(-1e6) == 0
        if (lane == 0) out[col] = 0.0f;
        return;                         // whole wave exits together
    }

    const int   rowbase = (col >> 9) << 9;   // b*N
    const float ang_j   = emb[col * 2] * PI_F;
    const int   id_j    = aid[col];
    const float be2     = b_e2[0];

    // per-wave V column into LDS (wave-synchronous; LDS ops in-order per wave)
    Vsh[wave][lane]      = V[col * 128 + lane];
    Vsh[wave][lane + 64] = V[col * 128 + 64 + lane];

    // Phase 1: ballot compaction of active rows
    int cnt = 0;
    #pragma unroll
    for (int rr = 0; rr < 8; ++rr) {
        int i  = lane + rr * 64;
        int gi = rowbase + i;
        float cls_i = cls[gi];
        bool m = (cls_i > cls_j) || (cls_i == cls_j && aid[gi] > id_j);
        if (m) m = fabsf(emb[gi * 2] * PI_F - ang_j) < 0.5f;
        unsigned long long bal = __ballot(m);
        int pre = __popcll(bal & ((1ull << lane) - 1ull));
        if (m) lists[wave][cnt + pre] = (unsigned short)i;
        cnt += __popcll(bal);
    }

    // Phase 2: dense per-row work over the compacted list
    float wm = 0.0f;
    for (int r = lane; r < cnt; r += 64) {
        int gi = rowbase + (int)lists[wave][r];
        const float4* Up = (const float4*)(U + gi * 128);
        float s = be2;
        #pragma unroll 8
        for (int k4 = 0; k4 < 32; ++k4) {
            float4 u4 = Up[k4];
            int k = k4 * 4;
            s += gelu_exact(u4.x - Vsh[wave][k + 0]) * w2s[k + 0];
            s += gelu_exact(u4.y - Vsh[wave][k + 1]) * w2s[k + 1];
            s += gelu_exact(u4.z - Vsh[wave][k + 2]) * w2s[k + 2];
            s += gelu_exact(u4.w - Vsh[wave][k + 3]) * w2s[k + 3];
        }
        wm = fmaxf(wm, s);
    }
    // wave max-reduce
    #pragma unroll
    for (int off = 32; off > 0; off >>= 1)
        wm = fmaxf(wm, __shfl_down(wm, off));
    const float nm = __shfl(wm, 0);

    // Phase 3: head MLP, one wave per column (lane = hidden dim)
    float n1 = fmaxf(nm * W_n1[lane] + b_n1[lane], 0.0f);
    n1sh[wave][lane] = n1;
    float a = b_n2[lane];
    #pragma unroll 8
    for (int m2 = 0; m2 < 64; ++m2) a += n1sh[wave][m2] * W_n2[m2 * 64 + lane];
    a = fmaxf(a, 0.0f);
    float p = a * W_hd[lane];
    #pragma unroll
    for (int off = 32; off > 0; off >>= 1) p += __shfl_down(p, off);
    if (lane == 0) {
        float logit = p + b_hd[0];
        out[col] = 1.0f / (1.0f + expf(-logit));
    }
}

extern "C" void kernel_launch(void* const* d_in, const int* in_sizes, int n_in,
                              void* d_out, int out_size, void* d_ws, size_t ws_size,
                              hipStream_t stream) {
    const float* bf    = (const float*)d_in[0];
    const float* cls   = (const float*)d_in[1];
    const int*   aid   = (const int*)  d_in[2];
    const float* emb   = (const float*)d_in[3];
    const float* W_cls = (const float*)d_in[4];
    const float* b_cls = (const float*)d_in[5];
    const float* W_pos = (const float*)d_in[6];
    const float* b_pos = (const float*)d_in[7];
    const float* W_in  = (const float*)d_in[8];
    const float* b_in  = (const float*)d_in[9];
    const float* W_out = (const float*)d_in[10];
    const float* b_out = (const float*)d_in[11];
    const float* W_e1  = (const float*)d_in[12];
    const float* b_e1  = (const float*)d_in[13];
    const float* W_e2  = (const float*)d_in[14];
    const float* b_e2  = (const float*)d_in[15];
    const float* W_n1  = (const float*)d_in[16];
    const float* b_n1  = (const float*)d_in[17];
    const float* W_n2  = (const float*)d_in[18];
    const float* b_n2  = (const float*)d_in[19];
    const float* W_hd  = (const float*)d_in[20];
    const float* b_hd  = (const float*)d_in[21];

    float* Uw = (float*)d_ws;            // [BN,128]
    float* Vw = Uw + BN * I;             // [BN,128]
    float* out = (float*)d_out;

    prep_kernel<<<BN / NPB, 256, 0, stream>>>(
        bf, emb, W_cls, b_cls, W_pos, b_pos, W_in, b_in, W_out, b_out,
        W_e1, b_e1, Uw, Vw);
    edge_kernel<<<BN / 4, 256, 0, stream>>>(
        Uw, Vw, cls, aid, emb, W_e2, b_e2, W_n1, b_n1, W_n2, b_n2,
        W_hd, b_hd, out);
}

// Round 3
// 133.173 us; speedup vs baseline: 3.1853x; 1.3735x over previous
//
#include <hip/hip_runtime.h>
#include <math.h>

// Problem constants (fixed by setup_inputs)
#define B  4
#define N  512
#define BN (B * N)
#define H  64
#define I  128

#define PI_F   3.14159265358979323846f
#define Y0_F   160.0f
#define Y1_F   155.4930028f   // 160 - 320*(1-1e-5)/71
#define INV_W  (1.0f / 800.0f)

// Fast tanh-GELU: x * sigmoid(2*y), y = x*(c0 + c1*x^2).
// |err vs exact erf-gelu| <= ~3e-3 worst case; propagates to <1e-4 at the
// sigmoid output (threshold 1e-2).
__device__ __forceinline__ float gelu_fast(float x) {
    float x2 = x * x;
    float t1 = __builtin_fmaf(x2, -2.0f * 0.0356774081f, -2.0f * 0.7978845608f);
    float e  = __expf(x * t1);                       // exp(-2y)
    return x * __builtin_amdgcn_rcpf(1.0f + e);
}

// ---------------------------------------------------------------------------
// Kernel A: per-node precompute (algebraic collapse of all per-edge matmuls).
//  feats = relu(bf @ W_cls + b_cls)                       [BN,64]
//  u = feats@W_in  + b_in  + p@W_pos + b_pos              [BN,128]
//  v = feats@W_out + b_out + p@W_pos                      [BN,128]
//  U = u @ W_e1 + b_e1 ;  V = v @ W_e1                    [BN,128]
// Then edge1[b,i,j,:] = U[b,i] - V[b,j]  exactly.
// 2-node weight sharing + 4 independent accumulator chains per thread.
// ---------------------------------------------------------------------------
#define NPB 4   // nodes per block -> 512 blocks (2/CU)

__global__ __launch_bounds__(256) void prep_kernel(
    const float* __restrict__ bf, const float* __restrict__ emb,
    const float* __restrict__ W_cls, const float* __restrict__ b_cls,
    const float* __restrict__ W_pos, const float* __restrict__ b_pos,
    const float* __restrict__ W_in,  const float* __restrict__ b_in,
    const float* __restrict__ W_out, const float* __restrict__ b_out,
    const float* __restrict__ W_e1,  const float* __restrict__ b_e1,
    float* __restrict__ Uo, float* __restrict__ Vo)
{
    __shared__ float sbf[NPB][64];
    __shared__ float sft[NPB][64];
    __shared__ float su[NPB][128];
    __shared__ float sv[NPB][128];
    __shared__ float sp[NPB][2];

    const int tid = threadIdx.x;
    const int node0 = blockIdx.x * NPB;

    // stage input rows (one value per thread) + per-node sample points
    {
        int nd = tid >> 6, d = tid & 63;
        sbf[nd][d] = bf[(node0 + nd) * 64 + d];
    }
    if (tid < NPB) {
        int g = node0 + tid;
        float ang = emb[g * 2] * PI_F;
        float t = tanf(ang);
        float rc = (emb[g * 2 + 1] * 800.0f) / cosf(ang);
        sp[tid][0] = (-t * Y0_F + rc) * INV_W;
        sp[tid][1] = (-t * Y1_F + rc) * INV_W;
    }
    __syncthreads();

    // Stage 1: feats = relu(bf @ W_cls + b_cls)   (4 acc chains)
    {
        int nd = tid >> 6, h = tid & 63;
        float a0 = 0.f, a1 = 0.f, a2 = 0.f, a3 = 0.f;
        #pragma unroll 4
        for (int d = 0; d < 64; d += 4) {
            a0 += sbf[nd][d + 0] * W_cls[(d + 0) * 64 + h];
            a1 += sbf[nd][d + 1] * W_cls[(d + 1) * 64 + h];
            a2 += sbf[nd][d + 2] * W_cls[(d + 2) * 64 + h];
            a3 += sbf[nd][d + 3] * W_cls[(d + 3) * 64 + h];
        }
        sft[nd][h] = fmaxf(b_cls[h] + ((a0 + a1) + (a2 + a3)), 0.0f);
    }
    __syncthreads();

    // Stage 2: u,v for 2 nodes per thread (weights loaded once, 4 chains)
    {
        int k = tid & 127, np = tid >> 7;     // np in {0,1}
        int n0 = np * 2, n1 = n0 + 1;
        float wp0 = W_pos[k], wp1 = W_pos[128 + k];
        float pe0 = sp[n0][0] * wp0 + sp[n0][1] * wp1;
        float pe1 = sp[n1][0] * wp0 + sp[n1][1] * wp1;
        float bi = b_in[k] + b_pos[k], bo = b_out[k];
        float au0 = 0.f, av0 = 0.f, au1 = 0.f, av1 = 0.f;
        #pragma unroll 8
        for (int h = 0; h < 64; ++h) {
            float wi = W_in[h * 128 + k];
            float wo = W_out[h * 128 + k];
            float f0 = sft[n0][h], f1 = sft[n1][h];
            au0 += f0 * wi;  av0 += f0 * wo;
            au1 += f1 * wi;  av1 += f1 * wo;
        }
        su[n0][k] = au0 + bi + pe0;  sv[n0][k] = av0 + bo + pe0;
        su[n1][k] = au1 + bi + pe1;  sv[n1][k] = av1 + bo + pe1;
    }
    __syncthreads();

    // Stage 3: U = u@W_e1 + b_e1 ; V = v@W_e1   (2 nodes/thread, 4 chains)
    {
        int k = tid & 127, np = tid >> 7;
        int n0 = np * 2, n1 = n0 + 1;
        float aU0 = 0.f, aV0 = 0.f, aU1 = 0.f, aV1 = 0.f;
        #pragma unroll 8
        for (int m = 0; m < 128; ++m) {
            float w = W_e1[m * 128 + k];
            aU0 += su[n0][m] * w;  aV0 += sv[n0][m] * w;
            aU1 += su[n1][m] * w;  aV1 += sv[n1][m] * w;
        }
        float be = b_e1[k];
        Uo[(node0 + n0) * 128 + k] = aU0 + be;
        Vo[(node0 + n0) * 128 + k] = aV0;
        Uo[(node0 + n1) * 128 + k] = aU1 + be;
        Vo[(node0 + n1) * 128 + k] = aV1;
    }
}

// ---------------------------------------------------------------------------
// Kernel B: ONE BLOCK PER COLUMN (4 waves cooperate).
// Phase 1: 4 waves mask 512 rows, ballot-compact into per-wave segments,
//          stitch into one LDS list.
// Phase 2: 256 threads each take ~1 compacted row (128 fast-gelu dot).
// Phase 3: shuffle max-reduce -> head MLP on wave 0 -> sigmoid.
// ---------------------------------------------------------------------------
__global__ __launch_bounds__(256) void edge_kernel(
    const float* __restrict__ U, const float* __restrict__ V,
    const float* __restrict__ cls, const int* __restrict__ aid,
    const float* __restrict__ emb,
    const float* __restrict__ W_e2, const float* __restrict__ b_e2,
    const float* __restrict__ W_n1, const float* __restrict__ b_n1,
    const float* __restrict__ W_n2, const float* __restrict__ b_n2,
    const float* __restrict__ W_hd, const float* __restrict__ b_hd,
    float* __restrict__ out)
{
    const int col  = blockIdx.x;          // b*N + j
    const int tid  = threadIdx.x;
    const int wave = tid >> 6;
    const int lane = tid & 63;

    __shared__ float Vs[128];
    __shared__ float w2s[128];
    __shared__ unsigned short lseg[4][128];
    __shared__ unsigned short list[512];
    __shared__ int wcnt[4];
    __shared__ float red[4];
    __shared__ float n1s[64];

    const float cls_j = cls[col];
    if (cls_j < 0.4f) {                   // masked column: sigmoid(-1e6) == 0
        if (tid == 0) out[col] = 0.0f;
        return;                           // uniform: whole block exits
    }

    if (tid < 128) {
        Vs[tid]  = V[col * 128 + tid];
        w2s[tid] = W_e2[tid];
    }

    const int   rowbase = (col >> 9) << 9;   // b*N
    const float ang_j   = emb[col * 2] * PI_F;
    const int   id_j    = aid[col];
    const float be2     = b_e2[0];

    // Phase 1: mask + per-wave ballot compaction (each wave: 128 rows)
    int c = 0;
    #pragma unroll
    for (int rr = 0; rr < 2; ++rr) {
        int i  = wave * 128 + rr * 64 + lane;
        int gi = rowbase + i;
        float ci = cls[gi];
        bool m = (ci > cls_j) || (ci == cls_j && aid[gi] > id_j);
        if (m) m = fabsf(emb[gi * 2] * PI_F - ang_j) < 0.5f;
        unsigned long long bal = __ballot(m);
        int pre = __popcll(bal & ((1ull << lane) - 1ull));
        if (m) lseg[wave][c + pre] = (unsigned short)i;
        c += __popcll(bal);
    }
    if (lane == 0) wcnt[wave] = c;
    __syncthreads();

    const int c0 = wcnt[0], c1 = wcnt[1], c2 = wcnt[2], c3 = wcnt[3];
    const int o1 = c0, o2 = c0 + c1, o3 = o2 + c2;
    const int total = o3 + c3;
    for (int r = tid; r < c0; r += 256) list[r]      = lseg[0][r];
    for (int r = tid; r < c1; r += 256) list[o1 + r] = lseg[1][r];
    for (int r = tid; r < c2; r += 256) list[o2 + r] = lseg[2][r];
    for (int r = tid; r < c3; r += 256) list[o3 + r] = lseg[3][r];
    __syncthreads();

    // Phase 2: one row per thread (usually), 4 accumulator chains
    float wm = 0.0f;
    const float4* V4 = (const float4*)Vs;
    const float4* g4 = (const float4*)w2s;
    for (int r = tid; r < total; r += 256) {
        int gi = rowbase + (int)list[r];
        const float4* Up = (const float4*)(U + gi * 128);
        float s0 = 0.f, s1 = 0.f, s2 = 0.f, s3 = 0.f;
        #pragma unroll 8
        for (int k4 = 0; k4 < 32; ++k4) {
            float4 u4 = Up[k4];
            float4 v4 = V4[k4];
            float4 w4 = g4[k4];
            s0 += gelu_fast(u4.x - v4.x) * w4.x;
            s1 += gelu_fast(u4.y - v4.y) * w4.y;
            s2 += gelu_fast(u4.z - v4.z) * w4.z;
            s3 += gelu_fast(u4.w - v4.w) * w4.w;
        }
        wm = fmaxf(wm, ((s0 + s1) + (s2 + s3)) + be2);
    }

    // Phase 3: max-reduce (shuffle within wave, LDS across waves)
    #pragma unroll
    for (int off = 32; off > 0; off >>= 1)
        wm = fmaxf(wm, __shfl_down(wm, off));
    if (lane == 0) red[wave] = wm;
    __syncthreads();

    if (wave == 0) {
        const float nm = fmaxf(fmaxf(red[0], red[1]), fmaxf(red[2], red[3]));
        // head MLP entirely on wave 0 (LDS in-order within a wave)
        n1s[lane] = fmaxf(nm * W_n1[lane] + b_n1[lane], 0.0f);
        float a = b_n2[lane];
        #pragma unroll 8
        for (int m2 = 0; m2 < 64; ++m2) a += n1s[m2] * W_n2[m2 * 64 + lane];
        a = fmaxf(a, 0.0f);
        float p = a * W_hd[lane];
        #pragma unroll
        for (int off = 32; off > 0; off >>= 1) p += __shfl_down(p, off);
        if (lane == 0) {
            float logit = p + b_hd[0];
            out[col] = 1.0f / (1.0f + expf(-logit));
        }
    }
}

extern "C" void kernel_launch(void* const* d_in, const int* in_sizes, int n_in,
                              void* d_out, int out_size, void* d_ws, size_t ws_size,
                              hipStream_t stream) {
    const float* bf    = (const float*)d_in[0];
    const float* cls   = (const float*)d_in[1];
    const int*   aid   = (const int*)  d_in[2];
    const float* emb   = (const float*)d_in[3];
    const float* W_cls = (const float*)d_in[4];
    const float* b_cls = (const float*)d_in[5];
    const float* W_pos = (const float*)d_in[6];
    const float* b_pos = (const float*)d_in[7];
    const float* W_in  = (const float*)d_in[8];
    const float* b_in  = (const float*)d_in[9];
    const float* W_out = (const float*)d_in[10];
    const float* b_out = (const float*)d_in[11];
    const float* W_e1  = (const float*)d_in[12];
    const float* b_e1  = (const float*)d_in[13];
    const float* W_e2  = (const float*)d_in[14];
    const float* b_e2  = (const float*)d_in[15];
    const float* W_n1  = (const float*)d_in[16];
    const float* b_n1  = (const float*)d_in[17];
    const float* W_n2  = (const float*)d_in[18];
    const float* b_n2  = (const float*)d_in[19];
    const float* W_hd  = (const float*)d_in[20];
    const float* b_hd  = (const float*)d_in[21];

    float* Uw = (float*)d_ws;            // [BN,128]
    float* Vw = Uw + BN * I;             // [BN,128]
    float* out = (float*)d_out;

    prep_kernel<<<BN / NPB, 256, 0, stream>>>(
        bf, emb, W_cls, b_cls, W_pos, b_pos, W_in, b_in, W_out, b_out,
        W_e1, b_e1, Uw, Vw);
    edge_kernel<<<BN, 256, 0, stream>>>(
        Uw, Vw, cls, aid, emb, W_e2, b_e2, W_n1, b_n1, W_n2, b_n2,
        W_hd, b_hd, out);
}